// Round 1
// baseline (358.236 us; speedup 1.0000x reference)
//
#include <hip/hip_runtime.h>

// one_hot @ weight where one_hot rows are exact {0,1} one-hot rows.
// Dense GEMM == row gather, bit-exact in fp32.
//
// Structure: ONE WAVE PER ROW (8192 waves = 32 waves/CU x 256 CU -> whole
// problem resident in a single occupancy round). Each wave scans its row in
// 1 KiB chunks (64 lanes x float4) with early exit via register-only
// __ballot/__shfl -- no LDS, no __syncthreads, uniform break. Then copies
// weight[idx] -> out[n] (4 KiB, 4 coalesced float4 iterations).
//
// Expected HBM traffic: ~50% of one_hot (128 MiB) + weight (<=32 MiB) +
// out (32 MiB) ~= 195 MiB -> ~31 us at 6.3 TB/s achievable.

constexpr int N_TOKENS = 8192;
constexpr int VOCAB    = 8192;
constexpr int D        = 1024;
constexpr int BLOCK    = 256;                     // 4 waves / block
constexpr int WPB      = BLOCK / 64;              // waves per block
constexpr int ROW_F4   = VOCAB / 4;               // 2048 float4 per row
constexpr int SCAN_IT  = ROW_F4 / 64;             // 32 chunk iterations max
constexpr int COPY_IT  = (D / 4) / 64;            // 4 float4 iterations

__global__ __launch_bounds__(BLOCK, 8) void onehot_gather_wave(
    const float* __restrict__ one_hot,
    const float* __restrict__ weight,
    float* __restrict__ out) {
    const int wid  = threadIdx.x >> 6;
    const int lane = threadIdx.x & 63;
    const int n    = blockIdx.x * WPB + wid;      // one wave per token row

    const float4* row = (const float4*)(one_hot + (size_t)n * VOCAB);

    int idx = -1;
    for (int it = 0; it < SCAN_IT; ++it) {
        const int pos  = it * 64 + lane;          // float4 index within row
        const float4 v = row[pos];
        const bool hit = (v.x != 0.f) || (v.y != 0.f) ||
                         (v.z != 0.f) || (v.w != 0.f);
        const unsigned long long m = __ballot(hit);
        if (m) {                                  // wave-uniform (ballot)
            const int off = (v.x != 0.f) ? 0 : (v.y != 0.f) ? 1
                          : (v.z != 0.f) ? 2 : 3;
            const int cand = pos * 4 + off;       // valid on hit lanes
            const int src  = __ffsll((long long)m) - 1;
            idx = __shfl(cand, src);              // broadcast from first hit
            break;
        }
    }

    float4* orow = (float4*)(out + (size_t)n * D);
    if (idx >= 0) {
        const float4* wrow = (const float4*)(weight + (size_t)idx * D);
#pragma unroll
        for (int j = 0; j < COPY_IT; ++j)
            orow[j * 64 + lane] = wrow[j * 64 + lane];
    } else {
        // all-zero one_hot row -> GEMM gives zeros
#pragma unroll
        for (int j = 0; j < COPY_IT; ++j)
            orow[j * 64 + lane] = make_float4(0.f, 0.f, 0.f, 0.f);
    }
}

extern "C" void kernel_launch(void* const* d_in, const int* in_sizes, int n_in,
                              void* d_out, int out_size, void* d_ws, size_t ws_size,
                              hipStream_t stream) {
    const float* one_hot = (const float*)d_in[0];   // [N_TOKENS, VOCAB] f32
    const float* weight  = (const float*)d_in[1];   // [VOCAB, D] f32
    float* out           = (float*)d_out;           // [N_TOKENS, D] f32

    onehot_gather_wave<<<dim3(N_TOKENS / WPB), dim3(BLOCK), 0, stream>>>(
        one_hot, weight, out);
}